// Round 10
// baseline (3339.482 us; speedup 1.0000x reference)
//
#include <hip/hip_runtime.h>
#include <stdint.h>

// LSTMClassifier on MI355X — round 22: R20 + per-wave word-flag publish.
// R21 post-mortem (3.1ms + a 33.8ms outlier): two confounded changes.
// (a) pre-poll e-MFMAs removed R20's h-load latency cover (steady loss);
// (b) atomicAdd counting publish = 128 RMWs/step on 2 cache lines racing
//     32 pollers -> contention, likely the 33.8ms near-livelock outlier.
// LESSON (R13/R19/R21 agree): per-step publish must be a plain RELAXED
// word store to a privately-owned word. No RMW, no sub-word, no release.
//
// This round: R20 verbatim (e-MFMAs post-barrier1 covering h-loads — the
// proven 2.40ms structure) with ONE isolated delta: barrier3 deleted.
// Each ks0 wave q of wg g drains its own h-stores (s_waitcnt vmcnt(0))
// then lane0 plain-stores flags[step+1][q*32+g]=1 (relaxed agent word).
// The four ks1 waves each poll their own quadrant's 32 words. Publish
// leaves as soon as THAT wave's epilogue lands (no wg-max + barrier).
// xbuf WAR safe: ks1 writes xbuf(t+1) after barrier1(t+1), which ks0
// reaches only after its epilogue(t) reads.
//
// Workspace (50.8 MiB): flags stride widened to 128 (513*128*4 = 262.7KB).

#define EMB   256
#define HID   512
#define NOUT  18
#define BATCH 64
#define SEQ   512
#define NPART 32     // scan workgroups = CUs on one XCD
#define WCOLS 16     // h-cols per wg (512/32)
#define FSTRIDE 128  // flags per step: 4 producer-waves x 32 wgs

typedef __attribute__((ext_vector_type(8))) short bf16x8;
typedef __attribute__((ext_vector_type(4))) float floatx4;

__device__ inline float bf2f(short u) {
    union { float f; uint32_t i; } v;
    v.i = ((uint32_t)(uint16_t)u) << 16;
    return v.f;
}
__device__ inline short f2bf(float f) {
    union { float f; uint32_t i; } v; v.f = f;
    uint32_t r = v.i + 0x7fffu + ((v.i >> 16) & 1u);   // RNE
    return (short)(r >> 16);
}
__device__ inline float sigm(float x) { return 1.f / (1.f + __expf(-x)); }
__device__ inline float tanh_fast(float x) {
    float xc = fminf(fmaxf(x, -15.f), 15.f);
    float e  = __expf(2.f * xc);
    return (e - 1.f) / (e + 1.f);
}

// Detect packed-bf16 vs fp32 float tensors (verified round 4 — keep).
__device__ inline bool detect_bf16(const void* emb_raw) {
    const uint32_t* w = (const uint32_t*)emb_raw;
    int votes = 0;
    #pragma unroll
    for (int i = 0; i < 8; i++) {
        uint32_t e = (w[i] >> 7) & 0xFFu;
        votes += (e >= 110u && e <= 135u) ? 1 : 0;
    }
    return votes >= 6;
}
__device__ inline float rd(const void* p, int idx, bool isbf) {
    return isbf ? bf2f(((const short*)p)[idx]) : ((const float*)p)[idx];
}

// load one 8-element bf16 fragment from a maybe-fp32 weight row
__device__ inline bf16x8 ldfrag(const void* base, size_t off, bool isbf) {
    if (isbf) return *(const bf16x8*)((const short*)base + off);
    const float* s = (const float*)base + off;
    bf16x8 v;
    #pragma unroll
    for (int j = 0; j < 8; j++) v[j] = f2bf(s[j]);
    return v;
}

// ---------------------------------------------------------------------------
// K0: e_seq[u][k] = emb[x[u&63][u>>6]][k] (bf16 out), u = s*64+b.
// ---------------------------------------------------------------------------
__global__ __launch_bounds__(256) void k0_gather(
    const int* __restrict__ x, const void* __restrict__ emb,
    short* __restrict__ eseq)
{
    const bool isbf = detect_bf16(emb);
    const int u0 = blockIdx.x * 32;
    #pragma unroll
    for (int it = 0; it < 4; it++) {
        int idx = it * 256 + threadIdx.x;          // 0..1023
        int u   = u0 + (idx >> 5);
        int ch  = (idx & 31) * 8;
        int tok = x[(u & 63) * SEQ + (u >> 6)];
        bf16x8 v;
        if (isbf) {
            v = *(const bf16x8*)((const short*)emb + (size_t)tok * EMB + ch);
        } else {
            const float* src = (const float*)emb + (size_t)tok * EMB + ch;
            #pragma unroll
            for (int j = 0; j < 8; j++) v[j] = f2bf(src[j]);
        }
        *(bf16x8*)(eseq + (size_t)u * EMB + ch) = v;
    }
}

// ---------------------------------------------------------------------------
// K2: intra-XCD persistent scan. Weights in LDS (96KB). 32 wgs x 512 thr.
// Wave w: q=w&3 (16 batch rows), ks=w>>2 (K half).
// ---------------------------------------------------------------------------
__global__ __launch_bounds__(512, 2) void k2_lstm(
    const void* __restrict__ w_hh, const void* __restrict__ w_ih,
    const void* __restrict__ b_ih, const void* __restrict__ b_hh,
    const void* __restrict__ emb, const short* __restrict__ eseq,
    short* __restrict__ hbuf, int* __restrict__ sync, int* __restrict__ flags)
{
    // 96 slots (nt*24+kk) x 64 lanes x 16B = 98,304 B of bf16 weight frags
    __shared__ short lds_w[96 * 64 * 8];
    // acc exchange: [q(4)][rg(4)][lane(64)][4 f32] = 16KB, lane-stride 16B
    // (verified: SQ_LDS_BANK_CONFLICT == 0 with this layout)
    __shared__ float xbuf[4 * 4 * 64 * 4];
    __shared__ float biasl[64];
    __shared__ int   sh_slot;

    const int t = threadIdx.x;

    // ---- XCD leader claim (round-9/10 verified; startup only).
    // Pigeonhole: 8*31 = 248 < 256 grid => some XCD always reaches NPART. ----
    if (t == 0) {
        unsigned xcd;
        asm volatile("s_getreg_b32 %0, hwreg(HW_REG_XCC_ID)" : "=s"(xcd));
        xcd &= 7u;
        int c = atomicAdd(&sync[8 + xcd], 1);
        if (c == NPART - 1) atomicCAS(&sync[0], 0, (int)xcd + 1);
        int L;
        while ((L = atomicAdd(&sync[0], 0)) == 0)
            __builtin_amdgcn_s_sleep(8);
        sh_slot = (L == (int)xcd + 1 && c < NPART) ? c : -1;
    }
    __syncthreads();
    const int g = sh_slot;
    if (g < 0) return;

    const bool isbf = detect_bf16(emb);
    const int lane = t & 63;
    const int w    = t >> 6;        // 0..7
    const int q    = w & 3;         // batch quadrant (16 rows)
    const int ks   = w >> 2;        // K half
    const int col  = lane & 15;
    const int quad = lane >> 4;

    // ---- stage weight fragments into LDS (bf16), once ----
    // slot = nt*24 + kk; kk 0..15 = W_hh (k=kk*32+q*8), kk 16..23 = W_ih.
    for (int item = t; item < 96 * 64; item += 512) {
        int slot = item >> 6;
        int ln   = item & 63;
        int nt   = slot / 24;
        int kk   = slot % 24;
        int c    = ln & 15, qq = ln >> 4;
        size_t grow = (size_t)(nt * HID + g * WCOLS + c);
        bf16x8 v;
        if (kk < 16) v = ldfrag(w_hh, grow * HID + kk * 32 + qq * 8, isbf);
        else         v = ldfrag(w_ih, grow * EMB + (kk - 16) * 32 + qq * 8, isbf);
        *(bf16x8*)(lds_w + (size_t)item * 8) = v;
    }
    if (t < 64) {
        int grow = (t >> 4) * HID + g * WCOLS + (t & 15);
        biasl[t] = rd(b_ih, grow, isbf) + rd(b_hh, grow, isbf);
    }
    __syncthreads();
    const float bI = biasl[col],      bF = biasl[16 + col];
    const float bG = biasl[32 + col], bO = biasl[48 + col];

    // per-lane base into the LDS frag table
    const short* lwl = lds_w + lane * 8;
#define LWF(nt, kk) (*(const bf16x8*)(lwl + (size_t)(((nt) * 24 + (kk)) * 64) * 8))

    float cre[4] = {0.f, 0.f, 0.f, 0.f};   // live in ks==0 waves only

    const int eoff = ks * 4;   // this wave's e-chunk base
    const int hoff = ks * 8;   // this wave's h-chunk base

    const short* eptr = eseq + (size_t)(q * 16 + col) * EMB + quad * 8;
    const short* hrd  = hbuf + (size_t)(q * 16 + col) * HID + quad * 8;
    short*       hwr  = hbuf + (size_t)(BATCH * HID)
                      + (size_t)(q * 16 + quad * 4) * HID + g * WCOLS + col;

    // prologue: e(0) into regs
    bf16x8 ae[4];
    #pragma unroll
    for (int kk = 0; kk < 4; kk++)
        ae[kk] = *(const bf16x8*)(eptr + (eoff + kk) * 32);

    // ---- scan ----
    for (int step = 0; step < SEQ; step++) {
        // pollers = the 4 ks1 waves; wave 4+q polls its own quadrant's 32
        // producer flags (RELAXED agent = sc1 L1-bypass, no inv). ks0 waves
        // go straight to the barrier.
        if (step > 0 && ks == 1 && lane < NPART) {
            int* fp = flags + (size_t)step * FSTRIDE + q * NPART + lane;
            int iters = 0;
            while (__hip_atomic_load(fp, __ATOMIC_RELAXED,
                                     __HIP_MEMORY_SCOPE_AGENT) == 0) {
                if (++iters > 16384) {
                    while (atomicAdd(fp, 0) == 0)   // word publish => RMW-safe
                        __builtin_amdgcn_s_sleep(8);
                    break;
                }
            }
        }
        __builtin_amdgcn_sched_barrier(0);
        __syncthreads();       // barrier1: h(step-1) published & in L2

        // issue h loads (the chain) and e(t+1) prefetch immediately
        bf16x8 ah[8];
        #pragma unroll
        for (int kk = 0; kk < 8; kk++)
            ah[kk] = *(const bf16x8*)(hrd + (hoff + kk) * 32);
        const short* pfp = (step < SEQ - 1) ? (eptr + (size_t)BATCH * EMB) : eptr;
        bf16x8 aen[4];
        #pragma unroll
        for (int kk = 0; kk < 4; kk++)
            aen[kk] = *(const bf16x8*)(pfp + (eoff + kk) * 32);
        __builtin_amdgcn_sched_barrier(0);   // pin load issue above compute

        floatx4 a0 = (floatx4){0.f,0.f,0.f,0.f}, a1 = a0, a2 = a0, a3 = a0;
        // e-MFMAs on prefetched regs + LDS B — covers h-load latency
        #pragma unroll
        for (int kk = 0; kk < 4; kk++) {
            a0 = __builtin_amdgcn_mfma_f32_16x16x32_bf16(ae[kk], LWF(0, 16+eoff+kk), a0, 0,0,0);
            a1 = __builtin_amdgcn_mfma_f32_16x16x32_bf16(ae[kk], LWF(1, 16+eoff+kk), a1, 0,0,0);
            a2 = __builtin_amdgcn_mfma_f32_16x16x32_bf16(ae[kk], LWF(2, 16+eoff+kk), a2, 0,0,0);
            a3 = __builtin_amdgcn_mfma_f32_16x16x32_bf16(ae[kk], LWF(3, 16+eoff+kk), a3, 0,0,0);
        }
        // h-MFMAs
        #pragma unroll
        for (int kk = 0; kk < 8; kk++) {
            a0 = __builtin_amdgcn_mfma_f32_16x16x32_bf16(ah[kk], LWF(0, hoff+kk), a0, 0,0,0);
            a1 = __builtin_amdgcn_mfma_f32_16x16x32_bf16(ah[kk], LWF(1, hoff+kk), a1, 0,0,0);
            a2 = __builtin_amdgcn_mfma_f32_16x16x32_bf16(ah[kk], LWF(2, hoff+kk), a2, 0,0,0);
            a3 = __builtin_amdgcn_mfma_f32_16x16x32_bf16(ah[kk], LWF(3, hoff+kk), a3, 0,0,0);
        }

        // ks1 waves export partials: [q][rg][lane][4] — lane-stride 16B
        if (ks == 1) {
            *(floatx4*)&xbuf[(((size_t)q * 4 + 0) * 64 + lane) * 4] = a0;
            *(floatx4*)&xbuf[(((size_t)q * 4 + 1) * 64 + lane) * 4] = a1;
            *(floatx4*)&xbuf[(((size_t)q * 4 + 2) * 64 + lane) * 4] = a2;
            *(floatx4*)&xbuf[(((size_t)q * 4 + 3) * 64 + lane) * 4] = a3;
        }
        __syncthreads();       // barrier2: partials visible

        if (ks == 0) {
            floatx4 p0 = *(const floatx4*)&xbuf[(((size_t)q * 4 + 0) * 64 + lane) * 4];
            floatx4 p1 = *(const floatx4*)&xbuf[(((size_t)q * 4 + 1) * 64 + lane) * 4];
            floatx4 p2 = *(const floatx4*)&xbuf[(((size_t)q * 4 + 2) * 64 + lane) * 4];
            floatx4 p3 = *(const floatx4*)&xbuf[(((size_t)q * 4 + 3) * 64 + lane) * 4];
            #pragma unroll
            for (int r = 0; r < 4; r++) {
                float iv = sigm(a0[r] + p0[r] + bI);
                float fv = sigm(a1[r] + p1[r] + bF);
                float gv = tanh_fast(a2[r] + p2[r] + bG);
                float ov = sigm(a3[r] + p3[r] + bO);
                cre[r] = fv * cre[r] + iv * gv;
                hwr[(size_t)r * HID] = f2bf(ov * tanh_fast(cre[r]));
            }
            // per-wave publish: drain THIS wave's h-stores to L2, then one
            // plain RELAXED word store to a privately-owned flag word.
            // (Proven-safe instruction class; no RMW, no sub-word, no release.)
            asm volatile("s_waitcnt vmcnt(0)" ::: "memory");
            if (lane == 0)
                __hip_atomic_store(
                    flags + (size_t)(step + 1) * FSTRIDE + q * NPART + g,
                    1, __ATOMIC_RELAXED, __HIP_MEMORY_SCOPE_AGENT);
        }
        // NO barrier3: waves proceed to next step. xbuf WAR safe via
        // barrier1(t+1); h(t) visibility carried by the per-wave flags.

        // rotate prefetched e into place; advance pointers
        ae[0] = aen[0]; ae[1] = aen[1]; ae[2] = aen[2]; ae[3] = aen[3];
        eptr = pfp;
        hrd += (size_t)BATCH * HID;
        hwr += (size_t)BATCH * HID;
    }
#undef LWF
}

// ---------------------------------------------------------------------------
// K3: logits = h_seq * W_fc^T + b_fc -> log_softmax(18). One token per thread.
// ---------------------------------------------------------------------------
__global__ __launch_bounds__(256) void k3_logits(
    const short* __restrict__ hbuf, const void* __restrict__ w_fc,
    const void* __restrict__ b_fc, const void* __restrict__ emb,
    void* __restrict__ out)
{
    __shared__ float Wf[NOUT][516];
    const bool isbf = detect_bf16(emb);
    const int t = threadIdx.x;
    for (int idx = t; idx < NOUT * 64; idx += 256) {
        int o = idx >> 6, ch = (idx & 63) * 8;
        #pragma unroll
        for (int j = 0; j < 8; j++)
            Wf[o][ch + j] = rd(w_fc, o * HID + ch + j, isbf);
    }
    __syncthreads();

    int u = blockIdx.x * 256 + t;              // u = s*64+b
    const short* hp = hbuf + (size_t)(u + BATCH) * HID;

    float acc[NOUT];
    #pragma unroll
    for (int o = 0; o < NOUT; o++) acc[o] = rd(b_fc, o, isbf);

    for (int ch = 0; ch < HID; ch += 8) {
        bf16x8 h8 = *(const bf16x8*)(hp + ch);
        float hf[8];
        #pragma unroll
        for (int j = 0; j < 8; j++) hf[j] = bf2f(h8[j]);
        #pragma unroll
        for (int o = 0; o < NOUT; o++) {
            floatx4 wa = *(const floatx4*)&Wf[o][ch];
            floatx4 wb = *(const floatx4*)&Wf[o][ch + 4];
            acc[o] += hf[0] * wa[0] + hf[1] * wa[1] + hf[2] * wa[2] + hf[3] * wa[3]
                    + hf[4] * wb[0] + hf[5] * wb[1] + hf[6] * wb[2] + hf[7] * wb[3];
        }
    }

    float mx = acc[0];
    #pragma unroll
    for (int o = 1; o < NOUT; o++) mx = fmaxf(mx, acc[o]);
    float s = 0.f;
    #pragma unroll
    for (int o = 0; o < NOUT; o++) s += __expf(acc[o] - mx);
    float lse = mx + __logf(s);

    int b = u & 63, sq = u >> 6;
    size_t base = (size_t)b * (SEQ * NOUT) + (size_t)sq * NOUT;
    if (isbf) {
        short* op = (short*)out + base;
        #pragma unroll
        for (int o = 0; o < NOUT; o++) op[o] = f2bf(acc[o] - lse);
    } else {
        float* op = (float*)out + base;
        #pragma unroll
        for (int o = 0; o < NOUT; o++) op[o] = acc[o] - lse;
    }
}

// ---------------------------------------------------------------------------
extern "C" void kernel_launch(void* const* d_in, const int* in_sizes, int n_in,
                              void* d_out, int out_size, void* d_ws, size_t ws_size,
                              hipStream_t stream) {
    const int*  x   = (const int*)d_in[0];
    const void* emb = d_in[1];
    const void* wih = d_in[2];
    const void* whh = d_in[3];
    const void* bih = d_in[4];
    const void* bhh = d_in[5];
    const void* wfc = d_in[6];
    const void* bfc = d_in[7];

    char*  ws    = (char*)d_ws;
    int*   sync  = (int*)ws;
    int*   flags = (int*)(ws + 4096);
    const size_t flagsz = (size_t)(SEQ + 1) * FSTRIDE * sizeof(int);  // 262.7KB
    short* hbuf  = (short*)(ws + 4096 + ((flagsz + 255) & ~(size_t)255));
    short* eseq  = (short*)((char*)hbuf + (size_t)(SEQ + 1) * BATCH * HID * 2);

    (void)hipMemsetAsync(sync, 0, 4096, stream);                    // claim
    (void)hipMemsetAsync(flags, 0, flagsz, stream);                 // flags = 0
    (void)hipMemsetAsync(hbuf, 0, (size_t)BATCH * HID * 2, stream); // h_0 = 0

    k0_gather<<<1024, 256, 0, stream>>>(x, emb, eseq);
    k2_lstm<<<256, 512, 0, stream>>>(whh, wih, bih, bhh, emb, eseq,
                                     hbuf, sync, flags);
    k3_logits<<<128, 256, 0, stream>>>(hbuf, wfc, bfc, emb, d_out);
}

// Round 11
// 2080.777 us; speedup vs baseline: 1.6049x; 1.6049x over previous
//
#include <hip/hip_runtime.h>
#include <stdint.h>

// LSTMClassifier on MI355X — round 23: batch-parallel rings (4 XCDs).
// R19/R21/R22 all proved the R20 sync skeleton (3 barriers, single t0
// relaxed-word publish, single wave-4 poller) cannot be beaten by publish
// restructuring — every alternative regressed. So keep it EXACTLY, and
// instead use the structure the math gives us: the LSTM recurrence is
// INDEPENDENT PER BATCH ROW. Split batch 64 into 4 rings of 16 rows, one
// ring per XCD (128 CUs active). Rings share nothing (h rows, flags, cre
// are ring-private) -> no cross-XCD traffic, no cross-ring jitter.
// Per-wg per-step work drops 4x: 96 MFMAs, 96 B-frag ds_read_b128 (no
// duplication: wave=(nt gate-tile, ks K-half), one floatx4 acc each),
// 8KB conflict-free exchange, epilogue 1 cell/thread (t<256).
// Claim: LDS 105KB => 1 wg/CU; grid 256 = CU count => EVERY XCD holds
// exactly 32 wgs => 4 rings always claimable. Protocol: per-XCD counter;
// 32nd wg claims a ring slot, maps xcd->ring (atomicExch), vmcnt-fence,
// bumps full-XCD count; waiters poll own mapping, and on full-count==8
// re-check mapping once before exiting. Deadlock-free by construction.
//
// Workspace (50.8 MiB): flags stride 128 (4 rings x 32) = 262.7KB (=R22 ok).

#define EMB   256
#define HID   512
#define NOUT  18
#define BATCH 64
#define SEQ   512
#define NPART 32     // wgs per ring = CUs per XCD
#define NRINGS 4     // rings (XCDs used); 16 batch rows each
#define WCOLS 16     // h-cols per wg (512/32)
#define FSTRIDE 128  // flags per step: NRINGS*NPART

typedef __attribute__((ext_vector_type(8))) short bf16x8;
typedef __attribute__((ext_vector_type(4))) float floatx4;

__device__ inline float bf2f(short u) {
    union { float f; uint32_t i; } v;
    v.i = ((uint32_t)(uint16_t)u) << 16;
    return v.f;
}
__device__ inline short f2bf(float f) {
    union { float f; uint32_t i; } v; v.f = f;
    uint32_t r = v.i + 0x7fffu + ((v.i >> 16) & 1u);   // RNE
    return (short)(r >> 16);
}
__device__ inline float sigm(float x) { return 1.f / (1.f + __expf(-x)); }
__device__ inline float tanh_fast(float x) {
    float xc = fminf(fmaxf(x, -15.f), 15.f);
    float e  = __expf(2.f * xc);
    return (e - 1.f) / (e + 1.f);
}

// Detect packed-bf16 vs fp32 float tensors (verified round 4 — keep).
__device__ inline bool detect_bf16(const void* emb_raw) {
    const uint32_t* w = (const uint32_t*)emb_raw;
    int votes = 0;
    #pragma unroll
    for (int i = 0; i < 8; i++) {
        uint32_t e = (w[i] >> 7) & 0xFFu;
        votes += (e >= 110u && e <= 135u) ? 1 : 0;
    }
    return votes >= 6;
}
__device__ inline float rd(const void* p, int idx, bool isbf) {
    return isbf ? bf2f(((const short*)p)[idx]) : ((const float*)p)[idx];
}

// load one 8-element bf16 fragment from a maybe-fp32 weight row
__device__ inline bf16x8 ldfrag(const void* base, size_t off, bool isbf) {
    if (isbf) return *(const bf16x8*)((const short*)base + off);
    const float* s = (const float*)base + off;
    bf16x8 v;
    #pragma unroll
    for (int j = 0; j < 8; j++) v[j] = f2bf(s[j]);
    return v;
}

// ---------------------------------------------------------------------------
// K0: e_seq[u][k] = emb[x[u&63][u>>6]][k] (bf16 out), u = s*64+b.
// ---------------------------------------------------------------------------
__global__ __launch_bounds__(256) void k0_gather(
    const int* __restrict__ x, const void* __restrict__ emb,
    short* __restrict__ eseq)
{
    const bool isbf = detect_bf16(emb);
    const int u0 = blockIdx.x * 32;
    #pragma unroll
    for (int it = 0; it < 4; it++) {
        int idx = it * 256 + threadIdx.x;          // 0..1023
        int u   = u0 + (idx >> 5);
        int ch  = (idx & 31) * 8;
        int tok = x[(u & 63) * SEQ + (u >> 6)];
        bf16x8 v;
        if (isbf) {
            v = *(const bf16x8*)((const short*)emb + (size_t)tok * EMB + ch);
        } else {
            const float* src = (const float*)emb + (size_t)tok * EMB + ch;
            #pragma unroll
            for (int j = 0; j < 8; j++) v[j] = f2bf(src[j]);
        }
        *(bf16x8*)(eseq + (size_t)u * EMB + ch) = v;
    }
}

// ---------------------------------------------------------------------------
// K2: 4 independent intra-XCD rings; ring r owns batch rows [16r,16r+16).
// 32 wgs/ring x 512 thr. Wave w: nt=w&3 (gate tile), ks=w>>2 (K half).
// Weights in LDS (96KB). R20-proven sync skeleton, ring-local.
// ---------------------------------------------------------------------------
__global__ __launch_bounds__(512, 2) void k2_lstm(
    const void* __restrict__ w_hh, const void* __restrict__ w_ih,
    const void* __restrict__ b_ih, const void* __restrict__ b_hh,
    const void* __restrict__ emb, const short* __restrict__ eseq,
    short* __restrict__ hbuf, int* __restrict__ sync, int* __restrict__ flags)
{
    // 96 slots (nt*24+kk) x 64 lanes x 16B = 98,304 B of bf16 weight frags
    __shared__ short lds_w[96 * 64 * 8];
    // acc exchange: [w(8)][lane(64)][4 f32] = 8KB, lane-stride 16B
    __shared__ float xbuf[8 * 64 * 4];
    __shared__ float biasl[64];
    __shared__ int   sh_slot;

    const int t = threadIdx.x;

    // ---- ring claim. 1 wg/CU (LDS) x grid 256 = all 8 XCDs hold exactly
    // 32 wgs. The 32nd wg of an XCD claims a ring (first NRINGS claimers). ----
    if (t == 0) {
        unsigned xcd;
        asm volatile("s_getreg_b32 %0, hwreg(HW_REG_XCC_ID)" : "=s"(xcd));
        xcd &= 7u;
        int c = atomicAdd(&sync[8 + xcd], 1);
        if (c == NPART - 1) {                       // 32nd wg on this XCD
            int rid = atomicAdd(&sync[2], 1);       // ring claim order
            if (rid < NRINGS)
                atomicExch(&sync[16 + xcd], rid + 1);   // xcd -> ring map
            asm volatile("s_waitcnt vmcnt(0)" ::: "memory");  // map before count
            atomicAdd(&sync[3], 1);                 // full-XCD count
        }
        int ring = -1;
        if (c < NPART) {
            while (true) {
                int m = atomicAdd(&sync[16 + xcd], 0);
                if (m) { ring = m - 1; break; }
                if (atomicAdd(&sync[3], 0) >= 8) {  // all XCDs full & mapped
                    int m2 = atomicAdd(&sync[16 + xcd], 0);
                    if (m2) ring = m2 - 1;
                    break;
                }
                __builtin_amdgcn_s_sleep(8);
            }
        }
        sh_slot = (ring >= 0) ? (ring * 64 + c) : -1;
    }
    __syncthreads();
    const int slot = sh_slot;
    if (slot < 0) return;
    const int ring = slot >> 6;     // 0..3
    const int g    = slot & 63;     // 0..31

    const bool isbf = detect_bf16(emb);
    const int lane = t & 63;
    const int w    = t >> 6;        // 0..7 == ks*4 + nt
    const int nt   = w & 3;         // gate tile
    const int ks   = w >> 2;        // K half
    const int arow = lane & 15;     // A row within the ring's 16-row tile
    const int quad = lane >> 4;

    // ---- stage weight fragments into LDS (bf16), once (as R16/R20) ----
    for (int item = t; item < 96 * 64; item += 512) {
        int sslot = item >> 6;
        int ln    = item & 63;
        int nts   = sslot / 24;
        int kk    = sslot % 24;
        int c2    = ln & 15, qq = ln >> 4;
        size_t grow = (size_t)(nts * HID + g * WCOLS + c2);
        bf16x8 v;
        if (kk < 16) v = ldfrag(w_hh, grow * HID + kk * 32 + qq * 8, isbf);
        else         v = ldfrag(w_ih, grow * EMB + (kk - 16) * 32 + qq * 8, isbf);
        *(bf16x8*)(lds_w + (size_t)item * 8) = v;
    }
    if (t < 64) {
        int grow = (t >> 4) * HID + g * WCOLS + (t & 15);
        biasl[t] = rd(b_ih, grow, isbf) + rd(b_hh, grow, isbf);
    }
    __syncthreads();
    // epilogue cell (threads 0..255): r = t>>4, c = t&15; c == lane&15
    const float bI = biasl[lane & 15],        bF = biasl[16 + (lane & 15)];
    const float bG = biasl[32 + (lane & 15)], bO = biasl[48 + (lane & 15)];

    const short* lwl = lds_w + lane * 8;
#define LWF(nt_, kk_) (*(const bf16x8*)(lwl + (size_t)((((nt_) * 24 + (kk_)) * 64)) * 8))

    float cre = 0.f;                // cell state (threads 0..255)

    const short* eptr = eseq + (size_t)(ring * 16 + arow) * EMB + quad * 8;
    const short* hrd  = hbuf + (size_t)(ring * 16 + arow) * HID + quad * 8;
    short*       hwp  = hbuf + (size_t)(BATCH * HID)
                      + (size_t)(ring * 16 + (t >> 4 & 15)) * HID
                      + g * WCOLS + (t & 15);   // valid for t<256

    // prologue: e(0) into regs
    bf16x8 ae[4];
    #pragma unroll
    for (int kk = 0; kk < 4; kk++)
        ae[kk] = *(const bf16x8*)(eptr + (ks * 4 + kk) * 32);

    // ---- scan (R20 skeleton, ring-local flags) ----
    for (int step = 0; step < SEQ; step++) {
        // poller = wave 4 (ks1,nt0): lanes 0..31 poll this ring's 32 flags
        // (RELAXED agent = sc1 L1-bypass, no inv).
        if (step > 0 && w == 4 && lane < NPART) {
            int* fp = flags + (size_t)step * FSTRIDE + ring * NPART + lane;
            int iters = 0;
            while (__hip_atomic_load(fp, __ATOMIC_RELAXED,
                                     __HIP_MEMORY_SCOPE_AGENT) == 0) {
                if (++iters > 16384) {
                    while (atomicAdd(fp, 0) == 0)   // word publish => RMW-safe
                        __builtin_amdgcn_s_sleep(8);
                    break;
                }
            }
        }
        __builtin_amdgcn_sched_barrier(0);
        __syncthreads();       // barrier1: h(step-1) published & in L2

        // issue h loads (the chain) and e(t+1) prefetch immediately
        bf16x8 ah[8];
        #pragma unroll
        for (int kk = 0; kk < 8; kk++)
            ah[kk] = *(const bf16x8*)(hrd + (ks * 8 + kk) * 32);
        const short* pfp = (step < SEQ - 1) ? (eptr + (size_t)BATCH * EMB) : eptr;
        bf16x8 aen[4];
        #pragma unroll
        for (int kk = 0; kk < 4; kk++)
            aen[kk] = *(const bf16x8*)(pfp + (ks * 4 + kk) * 32);
        __builtin_amdgcn_sched_barrier(0);   // pin load issue above compute

        // e-MFMAs on prefetched regs (cover h-load latency), then h-MFMAs
        floatx4 acc = (floatx4){0.f, 0.f, 0.f, 0.f};
        #pragma unroll
        for (int kk = 0; kk < 4; kk++)
            acc = __builtin_amdgcn_mfma_f32_16x16x32_bf16(
                      ae[kk], LWF(nt, 16 + ks * 4 + kk), acc, 0, 0, 0);
        #pragma unroll
        for (int kk = 0; kk < 8; kk++)
            acc = __builtin_amdgcn_mfma_f32_16x16x32_bf16(
                      ah[kk], LWF(nt, ks * 8 + kk), acc, 0, 0, 0);

        // all 8 waves export: [w][lane][4] — lane-stride 16B, conflict-free
        *(floatx4*)&xbuf[((size_t)w * 64 + lane) * 4] = acc;
        __syncthreads();       // barrier2: partials visible

        // epilogue: threads 0..255, one cell (r, c) each.
        // C layout: row = quad*4+reg, col = lane&15 => value for (r,c) sits
        // at xbuf[w][(r>>2)*16 + c][r&3], summed over ks (w and w+4).
        if (t < 256) {
            const int r  = t >> 4, c = t & 15;
            const int lw = (r >> 2) * 16 + c, rr = r & 3;
            float vI = xbuf[((size_t)(0) * 64 + lw) * 4 + rr]
                     + xbuf[((size_t)(4) * 64 + lw) * 4 + rr];
            float vF = xbuf[((size_t)(1) * 64 + lw) * 4 + rr]
                     + xbuf[((size_t)(5) * 64 + lw) * 4 + rr];
            float vG = xbuf[((size_t)(2) * 64 + lw) * 4 + rr]
                     + xbuf[((size_t)(6) * 64 + lw) * 4 + rr];
            float vO = xbuf[((size_t)(3) * 64 + lw) * 4 + rr]
                     + xbuf[((size_t)(7) * 64 + lw) * 4 + rr];
            float iv = sigm(vI + bI);
            float fv = sigm(vF + bF);
            float gv = tanh_fast(vG + bG);
            float ov = sigm(vO + bO);
            cre = fv * cre + iv * gv;
            *hwp = f2bf(ov * tanh_fast(cre));
        }

        // barrier3 drains every wave's vmcnt before s_barrier => all h-stores
        // committed to L2 when t0 publishes (R20-proven publish path).
        __syncthreads();
        if (t == 0)
            __hip_atomic_store(
                flags + (size_t)(step + 1) * FSTRIDE + ring * NPART + g,
                1, __ATOMIC_RELAXED, __HIP_MEMORY_SCOPE_AGENT);

        // rotate prefetched e into place; advance pointers
        ae[0] = aen[0]; ae[1] = aen[1]; ae[2] = aen[2]; ae[3] = aen[3];
        eptr = pfp;
        hrd += (size_t)BATCH * HID;
        hwp += (size_t)BATCH * HID;
    }
#undef LWF
}

// ---------------------------------------------------------------------------
// K3: logits = h_seq * W_fc^T + b_fc -> log_softmax(18). One token per thread.
// ---------------------------------------------------------------------------
__global__ __launch_bounds__(256) void k3_logits(
    const short* __restrict__ hbuf, const void* __restrict__ w_fc,
    const void* __restrict__ b_fc, const void* __restrict__ emb,
    void* __restrict__ out)
{
    __shared__ float Wf[NOUT][516];
    const bool isbf = detect_bf16(emb);
    const int t = threadIdx.x;
    for (int idx = t; idx < NOUT * 64; idx += 256) {
        int o = idx >> 6, ch = (idx & 63) * 8;
        #pragma unroll
        for (int j = 0; j < 8; j++)
            Wf[o][ch + j] = rd(w_fc, o * HID + ch + j, isbf);
    }
    __syncthreads();

    int u = blockIdx.x * 256 + t;              // u = s*64+b
    const short* hp = hbuf + (size_t)(u + BATCH) * HID;

    float acc[NOUT];
    #pragma unroll
    for (int o = 0; o < NOUT; o++) acc[o] = rd(b_fc, o, isbf);

    for (int ch = 0; ch < HID; ch += 8) {
        bf16x8 h8 = *(const bf16x8*)(hp + ch);
        float hf[8];
        #pragma unroll
        for (int j = 0; j < 8; j++) hf[j] = bf2f(h8[j]);
        #pragma unroll
        for (int o = 0; o < NOUT; o++) {
            floatx4 wa = *(const floatx4*)&Wf[o][ch];
            floatx4 wb = *(const floatx4*)&Wf[o][ch + 4];
            acc[o] += hf[0] * wa[0] + hf[1] * wa[1] + hf[2] * wa[2] + hf[3] * wa[3]
                    + hf[4] * wb[0] + hf[5] * wb[1] + hf[6] * wb[2] + hf[7] * wb[3];
        }
    }

    float mx = acc[0];
    #pragma unroll
    for (int o = 1; o < NOUT; o++) mx = fmaxf(mx, acc[o]);
    float s = 0.f;
    #pragma unroll
    for (int o = 0; o < NOUT; o++) s += __expf(acc[o] - mx);
    float lse = mx + __logf(s);

    int b = u & 63, sq = u >> 6;
    size_t base = (size_t)b * (SEQ * NOUT) + (size_t)sq * NOUT;
    if (isbf) {
        short* op = (short*)out + base;
        #pragma unroll
        for (int o = 0; o < NOUT; o++) op[o] = f2bf(acc[o] - lse);
    } else {
        float* op = (float*)out + base;
        #pragma unroll
        for (int o = 0; o < NOUT; o++) op[o] = acc[o] - lse;
    }
}

// ---------------------------------------------------------------------------
extern "C" void kernel_launch(void* const* d_in, const int* in_sizes, int n_in,
                              void* d_out, int out_size, void* d_ws, size_t ws_size,
                              hipStream_t stream) {
    const int*  x   = (const int*)d_in[0];
    const void* emb = d_in[1];
    const void* wih = d_in[2];
    const void* whh = d_in[3];
    const void* bih = d_in[4];
    const void* bhh = d_in[5];
    const void* wfc = d_in[6];
    const void* bfc = d_in[7];

    char*  ws    = (char*)d_ws;
    int*   sync  = (int*)ws;
    int*   flags = (int*)(ws + 4096);
    const size_t flagsz = (size_t)(SEQ + 1) * FSTRIDE * sizeof(int);  // 262.7KB
    short* hbuf  = (short*)(ws + 4096 + ((flagsz + 255) & ~(size_t)255));
    short* eseq  = (short*)((char*)hbuf + (size_t)(SEQ + 1) * BATCH * HID * 2);

    (void)hipMemsetAsync(sync, 0, 4096, stream);                    // claim
    (void)hipMemsetAsync(flags, 0, flagsz, stream);                 // flags = 0
    (void)hipMemsetAsync(hbuf, 0, (size_t)BATCH * HID * 2, stream); // h_0 = 0

    k0_gather<<<1024, 256, 0, stream>>>(x, emb, eseq);
    k2_lstm<<<256, 512, 0, stream>>>(whh, wih, bih, bhh, emb, eseq,
                                     hbuf, sync, flags);
    k3_logits<<<128, 256, 0, stream>>>(hbuf, wfc, bfc, emb, d_out);
}

// Round 12
// 1864.581 us; speedup vs baseline: 1.7910x; 1.1159x over previous
//
#include <hip/hip_runtime.h>
#include <stdint.h>

// LSTMClassifier on MI355X — round 24: spread flag lines + h-B frags in regs.
// R23 (best, 1.97ms k2, occupancy 11.9 = 4 rings confirmed). Remaining chain
// links attacked this round, sync skeleton untouched:
//  (1) A ring's 32 flags sat in ONE 128B cache line -> 32 producer stores
//      serialize on one L2 bank vs 32 poller loads, every step. New layout:
//      per-producer line-strided region flags[(ring*32+g)*FSTEP + step]
//      (FSTEP=560 words = 2240B, non-pow2 -> no channel aliasing). Producer
//      stores hit only their own line; poller lanes hit 32 distinct lines.
//  (2) h-MFMA B-fragments are LOOP-INVARIANT (8 frags = 32 VGPRs — small,
//      unlike R14/R17's 96+ frags): hoisted into registers before the loop.
//      Post-barrier chain becomes h-load -> MFMA with no ds_read in between.
//      VGPR 88+32=120 <= 128 keeps 2 waves/SIMD. Tell: VGPR ~120 = held.
//  4.2M bank conflicts = 2-way epilogue xbuf gather — measured-free, keep.
//
// Workspace (50.9 MiB): flags now 128 regions x 560 x 4B = 286.7KB.

#define EMB   256
#define HID   512
#define NOUT  18
#define BATCH 64
#define SEQ   512
#define NPART 32     // wgs per ring = CUs per XCD
#define NRINGS 4     // rings (XCDs used); 16 batch rows each
#define WCOLS 16     // h-cols per wg (512/32)
#define FSTEP 560    // words per producer flag region (>= SEQ+1, non-pow2)

typedef __attribute__((ext_vector_type(8))) short bf16x8;
typedef __attribute__((ext_vector_type(4))) float floatx4;

__device__ inline float bf2f(short u) {
    union { float f; uint32_t i; } v;
    v.i = ((uint32_t)(uint16_t)u) << 16;
    return v.f;
}
__device__ inline short f2bf(float f) {
    union { float f; uint32_t i; } v; v.f = f;
    uint32_t r = v.i + 0x7fffu + ((v.i >> 16) & 1u);   // RNE
    return (short)(r >> 16);
}
__device__ inline float sigm(float x) { return 1.f / (1.f + __expf(-x)); }
__device__ inline float tanh_fast(float x) {
    float xc = fminf(fmaxf(x, -15.f), 15.f);
    float e  = __expf(2.f * xc);
    return (e - 1.f) / (e + 1.f);
}

// Detect packed-bf16 vs fp32 float tensors (verified round 4 — keep).
__device__ inline bool detect_bf16(const void* emb_raw) {
    const uint32_t* w = (const uint32_t*)emb_raw;
    int votes = 0;
    #pragma unroll
    for (int i = 0; i < 8; i++) {
        uint32_t e = (w[i] >> 7) & 0xFFu;
        votes += (e >= 110u && e <= 135u) ? 1 : 0;
    }
    return votes >= 6;
}
__device__ inline float rd(const void* p, int idx, bool isbf) {
    return isbf ? bf2f(((const short*)p)[idx]) : ((const float*)p)[idx];
}

// load one 8-element bf16 fragment from a maybe-fp32 weight row
__device__ inline bf16x8 ldfrag(const void* base, size_t off, bool isbf) {
    if (isbf) return *(const bf16x8*)((const short*)base + off);
    const float* s = (const float*)base + off;
    bf16x8 v;
    #pragma unroll
    for (int j = 0; j < 8; j++) v[j] = f2bf(s[j]);
    return v;
}

// ---------------------------------------------------------------------------
// K0: e_seq[u][k] = emb[x[u&63][u>>6]][k] (bf16 out), u = s*64+b.
// ---------------------------------------------------------------------------
__global__ __launch_bounds__(256) void k0_gather(
    const int* __restrict__ x, const void* __restrict__ emb,
    short* __restrict__ eseq)
{
    const bool isbf = detect_bf16(emb);
    const int u0 = blockIdx.x * 32;
    #pragma unroll
    for (int it = 0; it < 4; it++) {
        int idx = it * 256 + threadIdx.x;          // 0..1023
        int u   = u0 + (idx >> 5);
        int ch  = (idx & 31) * 8;
        int tok = x[(u & 63) * SEQ + (u >> 6)];
        bf16x8 v;
        if (isbf) {
            v = *(const bf16x8*)((const short*)emb + (size_t)tok * EMB + ch);
        } else {
            const float* src = (const float*)emb + (size_t)tok * EMB + ch;
            #pragma unroll
            for (int j = 0; j < 8; j++) v[j] = f2bf(src[j]);
        }
        *(bf16x8*)(eseq + (size_t)u * EMB + ch) = v;
    }
}

// ---------------------------------------------------------------------------
// K2: 4 independent intra-XCD rings; ring r owns batch rows [16r,16r+16).
// 32 wgs/ring x 512 thr. Wave w: nt=w&3 (gate tile), ks=w>>2 (K half).
// Weights in LDS (96KB); h-B frags hoisted to regs. R20 sync skeleton.
// ---------------------------------------------------------------------------
__global__ __launch_bounds__(512, 2) void k2_lstm(
    const void* __restrict__ w_hh, const void* __restrict__ w_ih,
    const void* __restrict__ b_ih, const void* __restrict__ b_hh,
    const void* __restrict__ emb, const short* __restrict__ eseq,
    short* __restrict__ hbuf, int* __restrict__ sync, int* __restrict__ flags)
{
    // 96 slots (nt*24+kk) x 64 lanes x 16B = 98,304 B of bf16 weight frags
    __shared__ short lds_w[96 * 64 * 8];
    // acc exchange: [w(8)][lane(64)][4 f32] = 8KB, lane-stride 16B
    __shared__ float xbuf[8 * 64 * 4];
    __shared__ float biasl[64];
    __shared__ int   sh_slot;

    const int t = threadIdx.x;

    // ---- ring claim. 1 wg/CU (LDS) x grid 256 = all 8 XCDs hold exactly
    // 32 wgs. The 32nd wg of an XCD claims a ring (first NRINGS claimers). ----
    if (t == 0) {
        unsigned xcd;
        asm volatile("s_getreg_b32 %0, hwreg(HW_REG_XCC_ID)" : "=s"(xcd));
        xcd &= 7u;
        int c = atomicAdd(&sync[8 + xcd], 1);
        if (c == NPART - 1) {                       // 32nd wg on this XCD
            int rid = atomicAdd(&sync[2], 1);       // ring claim order
            if (rid < NRINGS)
                atomicExch(&sync[16 + xcd], rid + 1);   // xcd -> ring map
            asm volatile("s_waitcnt vmcnt(0)" ::: "memory");  // map before count
            atomicAdd(&sync[3], 1);                 // full-XCD count
        }
        int ring = -1;
        if (c < NPART) {
            while (true) {
                int m = atomicAdd(&sync[16 + xcd], 0);
                if (m) { ring = m - 1; break; }
                if (atomicAdd(&sync[3], 0) >= 8) {  // all XCDs full & mapped
                    int m2 = atomicAdd(&sync[16 + xcd], 0);
                    if (m2) ring = m2 - 1;
                    break;
                }
                __builtin_amdgcn_s_sleep(8);
            }
        }
        sh_slot = (ring >= 0) ? (ring * 64 + c) : -1;
    }
    __syncthreads();
    const int slot = sh_slot;
    if (slot < 0) return;
    const int ring = slot >> 6;     // 0..3
    const int g    = slot & 63;     // 0..31

    const bool isbf = detect_bf16(emb);
    const int lane = t & 63;
    const int w    = t >> 6;        // 0..7 == ks*4 + nt
    const int nt   = w & 3;         // gate tile
    const int ks   = w >> 2;        // K half
    const int arow = lane & 15;     // A row within the ring's 16-row tile
    const int quad = lane >> 4;

    // ---- stage weight fragments into LDS (bf16), once (as R16/R20) ----
    for (int item = t; item < 96 * 64; item += 512) {
        int sslot = item >> 6;
        int ln    = item & 63;
        int nts   = sslot / 24;
        int kk    = sslot % 24;
        int c2    = ln & 15, qq = ln >> 4;
        size_t grow = (size_t)(nts * HID + g * WCOLS + c2);
        bf16x8 v;
        if (kk < 16) v = ldfrag(w_hh, grow * HID + kk * 32 + qq * 8, isbf);
        else         v = ldfrag(w_ih, grow * EMB + (kk - 16) * 32 + qq * 8, isbf);
        *(bf16x8*)(lds_w + (size_t)item * 8) = v;
    }
    if (t < 64) {
        int grow = (t >> 4) * HID + g * WCOLS + (t & 15);
        biasl[t] = rd(b_ih, grow, isbf) + rd(b_hh, grow, isbf);
    }
    __syncthreads();
    // epilogue cell (threads 0..255): r = t>>4, c = t&15; c == lane&15
    const float bI = biasl[lane & 15],        bF = biasl[16 + (lane & 15)];
    const float bG = biasl[32 + (lane & 15)], bO = biasl[48 + (lane & 15)];

    const short* lwl = lds_w + lane * 8;
#define LWF(nt_, kk_) (*(const bf16x8*)(lwl + (size_t)((((nt_) * 24 + (kk_)) * 64)) * 8))

    // ---- h-MFMA B-fragments: LOOP-INVARIANT, hoisted to regs (32 VGPRs).
    // Small enough for the allocator to hold (R14/R17 failed at 96+ frags).
    bf16x8 bh[8];
    #pragma unroll
    for (int kk = 0; kk < 8; kk++)
        bh[kk] = LWF(nt, ks * 8 + kk);

    float cre = 0.f;                // cell state (threads 0..255)

    const short* eptr = eseq + (size_t)(ring * 16 + arow) * EMB + quad * 8;
    const short* hrd  = hbuf + (size_t)(ring * 16 + arow) * HID + quad * 8;
    short*       hwp  = hbuf + (size_t)(BATCH * HID)
                      + (size_t)(ring * 16 + (t >> 4 & 15)) * HID
                      + g * WCOLS + (t & 15);   // valid for t<256

    // per-producer flag region base (line-strided, no shared lines)
    int* const my_flag_region   = flags + (size_t)(ring * NPART + g) * FSTEP;
    int* const poll_flag_region = flags + (size_t)(ring * NPART + (lane & 31)) * FSTEP;

    // prologue: e(0) into regs
    bf16x8 ae[4];
    #pragma unroll
    for (int kk = 0; kk < 4; kk++)
        ae[kk] = *(const bf16x8*)(eptr + (ks * 4 + kk) * 32);

    // ---- scan (R20 skeleton, ring-local line-strided flags) ----
    for (int step = 0; step < SEQ; step++) {
        // poller = wave 4 (ks1,nt0): lanes 0..31 poll 32 DISTINCT cache
        // lines (RELAXED agent = sc1 L1-bypass, no inv).
        if (step > 0 && w == 4 && lane < NPART) {
            int* fp = poll_flag_region + step;
            int iters = 0;
            while (__hip_atomic_load(fp, __ATOMIC_RELAXED,
                                     __HIP_MEMORY_SCOPE_AGENT) == 0) {
                if (++iters > 16384) {
                    while (atomicAdd(fp, 0) == 0)   // word publish => RMW-safe
                        __builtin_amdgcn_s_sleep(8);
                    break;
                }
            }
        }
        __builtin_amdgcn_sched_barrier(0);
        __syncthreads();       // barrier1: h(step-1) published & in L2

        // issue h loads (the chain) and e(t+1) prefetch immediately
        bf16x8 ah[8];
        #pragma unroll
        for (int kk = 0; kk < 8; kk++)
            ah[kk] = *(const bf16x8*)(hrd + (ks * 8 + kk) * 32);
        const short* pfp = (step < SEQ - 1) ? (eptr + (size_t)BATCH * EMB) : eptr;
        bf16x8 aen[4];
        #pragma unroll
        for (int kk = 0; kk < 4; kk++)
            aen[kk] = *(const bf16x8*)(pfp + (ks * 4 + kk) * 32);
        __builtin_amdgcn_sched_barrier(0);   // pin load issue above compute

        // e-MFMAs on prefetched regs (cover h-load latency), then h-MFMAs
        // (B operands already in regs -> no ds_read on the critical path)
        floatx4 acc = (floatx4){0.f, 0.f, 0.f, 0.f};
        #pragma unroll
        for (int kk = 0; kk < 4; kk++)
            acc = __builtin_amdgcn_mfma_f32_16x16x32_bf16(
                      ae[kk], LWF(nt, 16 + ks * 4 + kk), acc, 0, 0, 0);
        #pragma unroll
        for (int kk = 0; kk < 8; kk++)
            acc = __builtin_amdgcn_mfma_f32_16x16x32_bf16(
                      ah[kk], bh[kk], acc, 0, 0, 0);

        // all 8 waves export: [w][lane][4] — lane-stride 16B, conflict-free
        *(floatx4*)&xbuf[((size_t)w * 64 + lane) * 4] = acc;
        __syncthreads();       // barrier2: partials visible

        // epilogue: threads 0..255, one cell (r, c) each.
        // C layout: row = quad*4+reg, col = lane&15 => value for (r,c) sits
        // at xbuf[w][(r>>2)*16 + c][r&3], summed over ks (w and w+4).
        if (t < 256) {
            const int r  = t >> 4, c = t & 15;
            const int lw = (r >> 2) * 16 + c, rr = r & 3;
            float vI = xbuf[((size_t)(0) * 64 + lw) * 4 + rr]
                     + xbuf[((size_t)(4) * 64 + lw) * 4 + rr];
            float vF = xbuf[((size_t)(1) * 64 + lw) * 4 + rr]
                     + xbuf[((size_t)(5) * 64 + lw) * 4 + rr];
            float vG = xbuf[((size_t)(2) * 64 + lw) * 4 + rr]
                     + xbuf[((size_t)(6) * 64 + lw) * 4 + rr];
            float vO = xbuf[((size_t)(3) * 64 + lw) * 4 + rr]
                     + xbuf[((size_t)(7) * 64 + lw) * 4 + rr];
            float iv = sigm(vI + bI);
            float fv = sigm(vF + bF);
            float gv = tanh_fast(vG + bG);
            float ov = sigm(vO + bO);
            cre = fv * cre + iv * gv;
            *hwp = f2bf(ov * tanh_fast(cre));
        }

        // barrier3 drains every wave's vmcnt before s_barrier => all h-stores
        // committed to L2 when t0 publishes (R20-proven publish path).
        __syncthreads();
        if (t == 0)
            __hip_atomic_store(my_flag_region + step + 1,
                               1, __ATOMIC_RELAXED, __HIP_MEMORY_SCOPE_AGENT);

        // rotate prefetched e into place; advance pointers
        ae[0] = aen[0]; ae[1] = aen[1]; ae[2] = aen[2]; ae[3] = aen[3];
        eptr = pfp;
        hrd += (size_t)BATCH * HID;
        hwp += (size_t)BATCH * HID;
    }
#undef LWF
}

// ---------------------------------------------------------------------------
// K3: logits = h_seq * W_fc^T + b_fc -> log_softmax(18). One token per thread.
// ---------------------------------------------------------------------------
__global__ __launch_bounds__(256) void k3_logits(
    const short* __restrict__ hbuf, const void* __restrict__ w_fc,
    const void* __restrict__ b_fc, const void* __restrict__ emb,
    void* __restrict__ out)
{
    __shared__ float Wf[NOUT][516];
    const bool isbf = detect_bf16(emb);
    const int t = threadIdx.x;
    for (int idx = t; idx < NOUT * 64; idx += 256) {
        int o = idx >> 6, ch = (idx & 63) * 8;
        #pragma unroll
        for (int j = 0; j < 8; j++)
            Wf[o][ch + j] = rd(w_fc, o * HID + ch + j, isbf);
    }
    __syncthreads();

    int u = blockIdx.x * 256 + t;              // u = s*64+b
    const short* hp = hbuf + (size_t)(u + BATCH) * HID;

    float acc[NOUT];
    #pragma unroll
    for (int o = 0; o < NOUT; o++) acc[o] = rd(b_fc, o, isbf);

    for (int ch = 0; ch < HID; ch += 8) {
        bf16x8 h8 = *(const bf16x8*)(hp + ch);
        float hf[8];
        #pragma unroll
        for (int j = 0; j < 8; j++) hf[j] = bf2f(h8[j]);
        #pragma unroll
        for (int o = 0; o < NOUT; o++) {
            floatx4 wa = *(const floatx4*)&Wf[o][ch];
            floatx4 wb = *(const floatx4*)&Wf[o][ch + 4];
            acc[o] += hf[0] * wa[0] + hf[1] * wa[1] + hf[2] * wa[2] + hf[3] * wa[3]
                    + hf[4] * wb[0] + hf[5] * wb[1] + hf[6] * wb[2] + hf[7] * wb[3];
        }
    }

    float mx = acc[0];
    #pragma unroll
    for (int o = 1; o < NOUT; o++) mx = fmaxf(mx, acc[o]);
    float s = 0.f;
    #pragma unroll
    for (int o = 0; o < NOUT; o++) s += __expf(acc[o] - mx);
    float lse = mx + __logf(s);

    int b = u & 63, sq = u >> 6;
    size_t base = (size_t)b * (SEQ * NOUT) + (size_t)sq * NOUT;
    if (isbf) {
        short* op = (short*)out + base;
        #pragma unroll
        for (int o = 0; o < NOUT; o++) op[o] = f2bf(acc[o] - lse);
    } else {
        float* op = (float*)out + base;
        #pragma unroll
        for (int o = 0; o < NOUT; o++) op[o] = acc[o] - lse;
    }
}

// ---------------------------------------------------------------------------
extern "C" void kernel_launch(void* const* d_in, const int* in_sizes, int n_in,
                              void* d_out, int out_size, void* d_ws, size_t ws_size,
                              hipStream_t stream) {
    const int*  x   = (const int*)d_in[0];
    const void* emb = d_in[1];
    const void* wih = d_in[2];
    const void* whh = d_in[3];
    const void* bih = d_in[4];
    const void* bhh = d_in[5];
    const void* wfc = d_in[6];
    const void* bfc = d_in[7];

    char*  ws    = (char*)d_ws;
    int*   sync  = (int*)ws;
    int*   flags = (int*)(ws + 4096);
    const size_t flagsz = (size_t)(NRINGS * NPART) * FSTEP * sizeof(int); // 286.7KB
    short* hbuf  = (short*)(ws + 4096 + ((flagsz + 255) & ~(size_t)255));
    short* eseq  = (short*)((char*)hbuf + (size_t)(SEQ + 1) * BATCH * HID * 2);

    (void)hipMemsetAsync(sync, 0, 4096, stream);                    // claim
    (void)hipMemsetAsync(flags, 0, flagsz, stream);                 // flags = 0
    (void)hipMemsetAsync(hbuf, 0, (size_t)BATCH * HID * 2, stream); // h_0 = 0

    k0_gather<<<1024, 256, 0, stream>>>(x, emb, eseq);
    k2_lstm<<<256, 512, 0, stream>>>(whh, wih, bih, bhh, emb, eseq,
                                     hbuf, sync, flags);
    k3_logits<<<128, 256, 0, stream>>>(hbuf, wfc, bfc, emb, d_out);
}